// Round 18
// baseline (317.928 us; speedup 1.0000x reference)
//
#include <hip/hip_runtime.h>
#include <hip/hip_bf16.h>
#include <hip/hip_fp16.h>

#define NNODES 50000
#define NEG_SLOPE 0.2f
#define BKT_SHIFT 8
#define NBKT ((NNODES + 255) >> 8)   // 196 buckets of 256 dsts
#define STRIDE 5120                   // fixed slots per bucket (avg 4082, +16 sigma)
#define PEPT 8                        // partition: edges per thread

typedef _Float16 half8 __attribute__((ext_vector_type(8)));
typedef float v4f __attribute__((ext_vector_type(4)));

__device__ __forceinline__ int rfl(int v) { return __builtin_amdgcn_readfirstlane(v); }

// ---------------- Kernel A: gemm0 (MFMA, on-the-fly W0 pack) + cursor init ----------
__global__ __launch_bounds__(256) void kernelA(
    const float* __restrict__ x, const float* __restrict__ W0,
    const float* __restrict__ AL, const float* __restrict__ AR,
    _Float16* __restrict__ featA, float2* __restrict__ el2A, float2* __restrict__ er2A,
    int* __restrict__ bcursor, int N) {
    int blk = blockIdx.x;
    if (blk == 782) {
        if (threadIdx.x < NBKT) bcursor[threadIdx.x * 16] = threadIdx.x * STRIDE;
        return;
    }
    int wave = threadIdx.x >> 6, lane = threadIdx.x & 63;
    int mtile = blk * 4 + wave;
    if (mtile * 16 >= N) return;
    int m0 = mtile * 16;
    int c = lane & 15, q = lane >> 4;
    v4f acc[4];
#pragma unroll
    for (int t = 0; t < 4; t++) acc[t] = (v4f){0.f, 0.f, 0.f, 0.f};
    const size_t arow = (size_t)(m0 + c) * 128 + q * 8;
#pragma unroll
    for (int kc = 0; kc < 4; kc++) {
        const float* xr = x + arow + kc * 32;
        float4 f0 = *(const float4*)xr;
        float4 f1 = *(const float4*)(xr + 4);
        float fv[8] = {f0.x, f0.y, f0.z, f0.w, f1.x, f1.y, f1.z, f1.w};
        half8 ah, av;
#pragma unroll
        for (int j = 0; j < 8; j++) {
            ah[j] = (_Float16)fv[j];
            av[j] = (_Float16)(fv[j] - (float)ah[j]);
        }
#pragma unroll
        for (int tt = 0; tt < 4; tt++) {
            half8 b;
#pragma unroll
            for (int j = 0; j < 8; j++)
                b[j] = (_Float16)W0[(size_t)(kc * 32 + q * 8 + j) * 64 + tt * 16 + c];
            acc[tt] = __builtin_amdgcn_mfma_f32_16x16x32_f16(ah, b, acc[tt], 0, 0, 0);
            acc[tt] = __builtin_amdgcn_mfma_f32_16x16x32_f16(av, b, acc[tt], 0, 0, 0);
        }
    }
#pragma unroll
    for (int tt = 0; tt < 4; tt++)
#pragma unroll
        for (int r = 0; r < 4; r++) {
            int row = m0 + q * 4 + r;
            featA[(size_t)row * 64 + tt * 16 + c] = (_Float16)acc[tt][r];
        }
    float alv[4], arv[4];
#pragma unroll
    for (int tt = 0; tt < 4; tt++) { alv[tt] = AL[tt * 16 + c]; arv[tt] = AR[tt * 16 + c]; }
#pragma unroll
    for (int r = 0; r < 4; r++) {
        float l0 = 0.f, l1 = 0.f, r0 = 0.f, r1 = 0.f;
#pragma unroll
        for (int tt = 0; tt < 4; tt++) {
            float v = acc[tt][r];
            if (tt < 2) { l0 = fmaf(v, alv[tt], l0); r0 = fmaf(v, arv[tt], r0); }
            else        { l1 = fmaf(v, alv[tt], l1); r1 = fmaf(v, arv[tt], r1); }
        }
#pragma unroll
        for (int m = 1; m < 16; m <<= 1) {
            l0 += __shfl_xor(l0, m, 64);
            l1 += __shfl_xor(l1, m, 64);
            r0 += __shfl_xor(r0, m, 64);
            r1 += __shfl_xor(r1, m, 64);
        }
        if (c == 0) {
            int row = m0 + q * 4 + r;
            el2A[row] = make_float2(l0, l1);
            er2A[row] = make_float2(r0, r1);
        }
    }
}

// ---------------- partition: block-privatized, fixed bucket regions ----------------
__global__ __launch_bounds__(1024) void partition_edges(
    const int* __restrict__ src, const int* __restrict__ dst,
    int* __restrict__ bcursor, int2* __restrict__ ebuf, int E) {
    __shared__ int hist[NBKT];
    __shared__ int gbase[NBKT];
    int t = threadIdx.x;
    for (int i = t; i < NBKT; i += 1024) hist[i] = 0;
    __syncthreads();
    int base = blockIdx.x * 1024 * PEPT;
    int sreg[PEPT], dreg[PEPT], rreg[PEPT], breg[PEPT];
#pragma unroll
    for (int k = 0; k < PEPT; k++) {
        int i = base + k * 1024 + t;
        if (i < E) {
            sreg[k] = src[i];
            dreg[k] = dst[i];
            breg[k] = dreg[k] >> BKT_SHIFT;
            rreg[k] = atomicAdd(&hist[breg[k]], 1);
        } else {
            breg[k] = -1;
        }
    }
    __syncthreads();
    for (int i = t; i < NBKT; i += 1024)
        if (hist[i]) gbase[i] = atomicAdd(&bcursor[i * 16], hist[i]);
    __syncthreads();
#pragma unroll
    for (int k = 0; k < PEPT; k++) {
        if (breg[k] >= 0)
            ebuf[(size_t)(gbase[breg[k]] + rreg[k])] = make_int2(sreg[k], dreg[k]);
    }
}

// ---------------- local sort: per-bucket degree count + scan -> rowse + csrc ----
__global__ __launch_bounds__(256) void local_sort(const int2* __restrict__ ebuf,
                                                  const int* __restrict__ bcursor,
                                                  int2* __restrict__ rowse,
                                                  int* __restrict__ csrc, int N) {
    __shared__ int lcnt[256], lrow[256], ws[4];
    int b = blockIdx.x;
    int d0 = b << BKT_SHIFT;
    int t = threadIdx.x;
    int base = b * STRIDE;
    int endE = bcursor[b * 16];
    lcnt[t] = 0;
    __syncthreads();
    for (int i = base + t; i < endE; i += 256)
        atomicAdd(&lcnt[ebuf[i].y - d0], 1);
    __syncthreads();
    int v = lcnt[t];
    int lane = t & 63;
    int x = v;
#pragma unroll
    for (int m = 1; m < 64; m <<= 1) {
        int y = __shfl_up(x, m, 64);
        if (lane >= m) x += y;
    }
    if (lane == 63) ws[t >> 6] = x;
    __syncthreads();
    int w = t >> 6, waveoff = 0;
#pragma unroll
    for (int k = 0; k < 4; k++) if (k < w) waveoff += ws[k];
    int excl = base + waveoff + x - v;
    lrow[t] = excl;
    int d = d0 + t;
    if (d < N) rowse[d] = make_int2(excl, excl + v);
    lcnt[t] = 0;
    __syncthreads();
    for (int i = base + t; i < endE; i += 256) {
        int2 e = ebuf[i];
        int ld = e.y - d0;
        int p = lrow[ld] + atomicAdd(&lcnt[ld], 1);
        csrc[p] = e.x;
    }
}

// ---------------- agg0 + fused fp32 matvec gemm1 (64->64) + layer-1 logits ----
// W1 column in registers (natural VGPR ~60, no cap -> no spill; R14/R15 lesson).
__global__ __launch_bounds__(256) void agg0_gemm1(
    const int2* __restrict__ rowse, const int* __restrict__ csrc,
    const float2* __restrict__ el2A, const float2* __restrict__ er2A,
    const _Float16* __restrict__ featA, const float* __restrict__ b0,
    const float* __restrict__ W1, const float* __restrict__ al1, const float* __restrict__ ar1,
    _Float16* __restrict__ featB, float2* __restrict__ el2B, float2* __restrict__ er2B,
    int N) {
    __shared__ int2 stA[4][64], stB[4][64];
    __shared__ float vbuf[4][64];
    int wave = threadIdx.x >> 6, lane = threadIdx.x & 63, h = lane >> 5;
    float bl = b0[lane];
    float w1r[64];
#pragma unroll
    for (int k = 0; k < 64; k++) w1r[k] = W1[k * 64 + lane];
    float al1v = al1[lane], ar1v = ar1[lane];
    const int2* stH = h ? stB[wave] : stA[wave];
    for (int n0 = blockIdx.x * 4 + wave; n0 < N; n0 += gridDim.x * 4) {
        int n = rfl(n0);
        int2 se = rowse[n];
        int beg = rfl(se.x), end = rfl(se.y);
        float2 rr = er2A[n];
        float s = 0.f, acc = 0.f;
        for (int base = beg; base < end; base += 64) {
            int idx = base + lane;
            int sv = 0; float wxv = 0.f, wyv = 0.f;
            if (idx < end) {
                sv = csrc[idx];
                float2 l = el2A[sv];
                float t0 = l.x + rr.x; t0 = t0 > 0.f ? t0 : NEG_SLOPE * t0;
                float t1 = l.y + rr.y; t1 = t1 > 0.f ? t1 : NEG_SLOPE * t1;
                wxv = __expf(t0); wyv = __expf(t1);
            }
            stA[wave][lane] = make_int2(sv, __float_as_int(wxv));
            stB[wave][lane] = make_int2(sv, __float_as_int(wyv));
            int cnt = min(64, end - base);
            int j = 0;
            for (; j + 7 < cnt; j += 8) {
                int4 e01 = *(const int4*)(stH + j);
                int4 e23 = *(const int4*)(stH + j + 2);
                int4 e45 = *(const int4*)(stH + j + 4);
                int4 e67 = *(const int4*)(stH + j + 6);
                float f0 = (float)featA[(size_t)e01.x * 64 + lane];
                float f1 = (float)featA[(size_t)e01.z * 64 + lane];
                float f2 = (float)featA[(size_t)e23.x * 64 + lane];
                float f3 = (float)featA[(size_t)e23.z * 64 + lane];
                float f4 = (float)featA[(size_t)e45.x * 64 + lane];
                float f5 = (float)featA[(size_t)e45.z * 64 + lane];
                float f6 = (float)featA[(size_t)e67.x * 64 + lane];
                float f7 = (float)featA[(size_t)e67.z * 64 + lane];
                float w0 = __int_as_float(e01.y), w1 = __int_as_float(e01.w);
                float w2 = __int_as_float(e23.y), w3 = __int_as_float(e23.w);
                float w4 = __int_as_float(e45.y), w5 = __int_as_float(e45.w);
                float w6 = __int_as_float(e67.y), w7 = __int_as_float(e67.w);
                s += ((w0 + w1) + (w2 + w3)) + ((w4 + w5) + (w6 + w7));
                acc = fmaf(w0, f0, acc);
                acc = fmaf(w1, f1, acc);
                acc = fmaf(w2, f2, acc);
                acc = fmaf(w3, f3, acc);
                acc = fmaf(w4, f4, acc);
                acc = fmaf(w5, f5, acc);
                acc = fmaf(w6, f6, acc);
                acc = fmaf(w7, f7, acc);
            }
            for (; j < cnt; j++) {
                int2 e = stH[j];
                float w0 = __int_as_float(e.y);
                float f0 = (float)featA[(size_t)e.x * 64 + lane];
                s += w0;
                acc = fmaf(w0, f0, acc);
            }
        }
        float v = (s > 0.f) ? acc / s : 0.f;
        v = fmaxf(v + bl, 0.f);
        vbuf[wave][lane] = v;
        const float4* vv = (const float4*)vbuf[wave];
        float f = 0.f;
#pragma unroll
        for (int kk = 0; kk < 16; kk++) {
            float4 v4 = vv[kk];
            f = fmaf(v4.x, w1r[4 * kk + 0], f);
            f = fmaf(v4.y, w1r[4 * kk + 1], f);
            f = fmaf(v4.z, w1r[4 * kk + 2], f);
            f = fmaf(v4.w, w1r[4 * kk + 3], f);
        }
        featB[(size_t)n * 64 + lane] = (_Float16)f;
        float vl = f * al1v, vr = f * ar1v;
#pragma unroll
        for (int m = 1; m < 32; m <<= 1) {
            vl += __shfl_xor(vl, m, 64);
            vr += __shfl_xor(vr, m, 64);
        }
        if ((lane & 31) == 0) {
            ((float*)el2B)[n * 2 + h] = vl;
            ((float*)er2B)[n * 2 + h] = vr;
        }
    }
}

// ---------------- agg1 + fused fp32 matvec gemm2 (64->128) + layer-2 logits ----
// W2 staged in LDS (32 KB won't fit registers): W2T[c][k], stride 65 == 1 (mod 32)
// -> lane c's ds_read_b128 conflict-free (upper 32 lanes 2-way alias = free).
// Replaces aggregate32 + gemm_mfma2 and the ahi/alo hi/lo fp16 round-trip;
// fp32 matvec is MORE accurate than the hi/lo MFMA it replaces.
__global__ __launch_bounds__(256) void agg1_gemm2(
    const int2* __restrict__ rowse, const int* __restrict__ csrc,
    const float2* __restrict__ el2B, const float2* __restrict__ er2B,
    const _Float16* __restrict__ featB, const float* __restrict__ b1,
    const float* __restrict__ W2, const float* __restrict__ al2, const float* __restrict__ ar2,
    __half2* __restrict__ featC, float2* __restrict__ el2C, float2* __restrict__ er2C,
    int N) {
    __shared__ int2 stA[4][64], stB[4][64];
    __shared__ float vbuf[4][64];
    __shared__ float W2T[128][65];   // W2T[c][k] = W2[k][c]
    int wave = threadIdx.x >> 6, lane = threadIdx.x & 63, h = lane >> 5;
    for (int idx = threadIdx.x; idx < 8192; idx += 256) {
        int k = idx >> 7, c = idx & 127;
        W2T[c][k] = W2[idx];         // coalesced global read
    }
    __syncthreads();
    float bl = b1[lane];
    float al2a = al2[lane], al2b = al2[64 + lane];
    float ar2a = ar2[lane], ar2b = ar2[64 + lane];
    const int2* stH = h ? stB[wave] : stA[wave];
    for (int n0 = blockIdx.x * 4 + wave; n0 < N; n0 += gridDim.x * 4) {
        int n = rfl(n0);
        int2 se = rowse[n];
        int beg = rfl(se.x), end = rfl(se.y);
        float2 rr = er2B[n];
        float s = 0.f, acc = 0.f;
        for (int base = beg; base < end; base += 64) {
            int idx = base + lane;
            int sv = 0; float wxv = 0.f, wyv = 0.f;
            if (idx < end) {
                sv = csrc[idx];
                float2 l = el2B[sv];
                float t0 = l.x + rr.x; t0 = t0 > 0.f ? t0 : NEG_SLOPE * t0;
                float t1 = l.y + rr.y; t1 = t1 > 0.f ? t1 : NEG_SLOPE * t1;
                wxv = __expf(t0); wyv = __expf(t1);
            }
            stA[wave][lane] = make_int2(sv, __float_as_int(wxv));
            stB[wave][lane] = make_int2(sv, __float_as_int(wyv));
            int cnt = min(64, end - base);
            int j = 0;
            for (; j + 7 < cnt; j += 8) {
                int4 e01 = *(const int4*)(stH + j);
                int4 e23 = *(const int4*)(stH + j + 2);
                int4 e45 = *(const int4*)(stH + j + 4);
                int4 e67 = *(const int4*)(stH + j + 6);
                float f0 = (float)featB[(size_t)e01.x * 64 + lane];
                float f1 = (float)featB[(size_t)e01.z * 64 + lane];
                float f2 = (float)featB[(size_t)e23.x * 64 + lane];
                float f3 = (float)featB[(size_t)e23.z * 64 + lane];
                float f4 = (float)featB[(size_t)e45.x * 64 + lane];
                float f5 = (float)featB[(size_t)e45.z * 64 + lane];
                float f6 = (float)featB[(size_t)e67.x * 64 + lane];
                float f7 = (float)featB[(size_t)e67.z * 64 + lane];
                float w0 = __int_as_float(e01.y), w1 = __int_as_float(e01.w);
                float w2 = __int_as_float(e23.y), w3 = __int_as_float(e23.w);
                float w4 = __int_as_float(e45.y), w5 = __int_as_float(e45.w);
                float w6 = __int_as_float(e67.y), w7 = __int_as_float(e67.w);
                s += ((w0 + w1) + (w2 + w3)) + ((w4 + w5) + (w6 + w7));
                acc = fmaf(w0, f0, acc);
                acc = fmaf(w1, f1, acc);
                acc = fmaf(w2, f2, acc);
                acc = fmaf(w3, f3, acc);
                acc = fmaf(w4, f4, acc);
                acc = fmaf(w5, f5, acc);
                acc = fmaf(w6, f6, acc);
                acc = fmaf(w7, f7, acc);
            }
            for (; j < cnt; j++) {
                int2 e = stH[j];
                float w0 = __int_as_float(e.y);
                float f0 = (float)featB[(size_t)e.x * 64 + lane];
                s += w0;
                acc = fmaf(w0, f0, acc);
            }
        }
        float v = (s > 0.f) ? acc / s : 0.f;
        v = fmaxf(v + bl, 0.f);
        // fused gemm2: f0 = col `lane` (head0), f1 = col `64+lane` (head1), fp32
        vbuf[wave][lane] = v;
        const float4* vv = (const float4*)vbuf[wave];
        const float4* w0r = (const float4*)&W2T[lane][0];
        const float4* w1r = (const float4*)&W2T[64 + lane][0];
        float f0 = 0.f, f1 = 0.f;
#pragma unroll
        for (int kk = 0; kk < 16; kk++) {
            float4 vq = vv[kk];
            float4 a4 = w0r[kk];
            float4 b4 = w1r[kk];
            f0 = fmaf(vq.x, a4.x, f0); f1 = fmaf(vq.x, b4.x, f1);
            f0 = fmaf(vq.y, a4.y, f0); f1 = fmaf(vq.y, b4.y, f1);
            f0 = fmaf(vq.z, a4.z, f0); f1 = fmaf(vq.z, b4.z, f1);
            f0 = fmaf(vq.w, a4.w, f0); f1 = fmaf(vq.w, b4.w, f1);
        }
        featC[(size_t)n * 64 + lane] = __floats2half2_rn(f0, f1);
        float l0 = f0 * al2a, l1 = f1 * al2b;
        float r0 = f0 * ar2a, r1 = f1 * ar2b;
#pragma unroll
        for (int m = 1; m < 64; m <<= 1) {
            l0 += __shfl_xor(l0, m, 64);
            l1 += __shfl_xor(l1, m, 64);
            r0 += __shfl_xor(r0, m, 64);
            r1 += __shfl_xor(r1, m, 64);
        }
        if (lane == 0) {
            el2C[n] = make_float2(l0, l1);
            er2C[n] = make_float2(r0, r1);
        }
    }
}

// ---------------- agg2: both heads via half2; mean over heads ----------------
__global__ __launch_bounds__(256) void aggregate64_mean(
    const int2* __restrict__ rowse, const int* __restrict__ csrc,
    const float2* __restrict__ el2, const float2* __restrict__ er2,
    const __half2* __restrict__ feat2, const float* __restrict__ b,
    float* __restrict__ out, int N) {
    __shared__ int4 st[4][64];
    int wave = threadIdx.x >> 6, lane = threadIdx.x & 63;
    int n = rfl(blockIdx.x * 4 + wave);
    if (n >= N) return;
    float b0 = b[lane], b1 = b[64 + lane];
    int2 se = rowse[n];
    int beg = rfl(se.x), end = rfl(se.y);
    float2 rr = er2[n];
    float s0 = 0.f, s1 = 0.f, a0 = 0.f, a1 = 0.f;
    for (int base = beg; base < end; base += 64) {
        int idx = base + lane;
        int sv = 0; float wxv = 0.f, wyv = 0.f;
        if (idx < end) {
            sv = csrc[idx];
            float2 l = el2[sv];
            float t0 = l.x + rr.x; t0 = t0 > 0.f ? t0 : NEG_SLOPE * t0;
            float t1 = l.y + rr.y; t1 = t1 > 0.f ? t1 : NEG_SLOPE * t1;
            wxv = __expf(t0); wyv = __expf(t1);
        }
        st[wave][lane] = make_int4(sv, __float_as_int(wxv), __float_as_int(wyv), 0);
        int cnt = min(64, end - base);
        int j = 0;
        for (; j + 7 < cnt; j += 8) {
            float2 fv[8]; float wxs[8], wys[8];
#pragma unroll
            for (int u = 0; u < 8; u++) {
                int4 e = st[wave][j + u];
                wxs[u] = __int_as_float(e.y);
                wys[u] = __int_as_float(e.z);
                fv[u] = __half22float2(feat2[(size_t)e.x * 64 + lane]);
            }
#pragma unroll
            for (int u = 0; u < 8; u++) {
                s0 += wxs[u]; s1 += wys[u];
                a0 = fmaf(wxs[u], fv[u].x, a0);
                a1 = fmaf(wys[u], fv[u].y, a1);
            }
        }
        for (; j < cnt; j++) {
            int4 e = st[wave][j];
            float wx0 = __int_as_float(e.y), wy0 = __int_as_float(e.z);
            float2 f0 = __half22float2(feat2[(size_t)e.x * 64 + lane]);
            s0 += wx0; s1 += wy0;
            a0 = fmaf(wx0, f0.x, a0); a1 = fmaf(wy0, f0.y, a1);
        }
    }
    float v0 = (s0 > 0.f) ? a0 / s0 : 0.f;
    float v1 = (s1 > 0.f) ? a1 / s1 : 0.f;
    out[(size_t)n * 64 + lane] = 0.5f * ((v0 + b0) + (v1 + b1));
}

// ---------------- launcher ----------------

extern "C" void kernel_launch(void* const* d_in, const int* in_sizes, int n_in,
                              void* d_out, int out_size, void* d_ws, size_t ws_size,
                              hipStream_t stream) {
    const float* x   = (const float*)d_in[0];
    const int*   src = (const int*)d_in[1];
    const int*   dst = (const int*)d_in[2];
    const float* W0  = (const float*)d_in[3];
    const float* al0 = (const float*)d_in[4];
    const float* ar0 = (const float*)d_in[5];
    const float* b0  = (const float*)d_in[6];
    const float* W1  = (const float*)d_in[7];
    const float* al1 = (const float*)d_in[8];
    const float* ar1 = (const float*)d_in[9];
    const float* b1  = (const float*)d_in[10];
    const float* W2  = (const float*)d_in[11];
    const float* al2 = (const float*)d_in[12];
    const float* ar2 = (const float*)d_in[13];
    const float* b2  = (const float*)d_in[14];
    float* out = (float*)d_out;

    const int N = NNODES;
    const int E = in_sizes[1];

    char* p = (char*)d_ws;
    auto alloc = [&](size_t bytes) {
        void* r = (void*)p;
        p += (bytes + 255) & ~(size_t)255;
        return r;
    };
    int*    bcursor = (int*)alloc((size_t)NBKT * 16 * 4);
    int2*   rowse   = (int2*)alloc((size_t)N * 8);
    int2*   ebuf    = (int2*)alloc(((size_t)NBKT * STRIDE + 4096) * 8);
    int*    csrc    = (int*)alloc(((size_t)NBKT * STRIDE + 4096) * 4);
    float2* el2A    = (float2*)alloc((size_t)N * 8);
    float2* er2A    = (float2*)alloc((size_t)N * 8);
    float2* el2B    = (float2*)alloc((size_t)N * 8);
    float2* er2B    = (float2*)alloc((size_t)N * 8);
    void*   featA   = alloc((size_t)N * 64 * 4);    // fp16[N][64] (L0) -> half2[N][64] (L2)
    _Float16* featB = (_Float16*)alloc((size_t)N * 64 * 2);  // fp16[N][64] (L1)

    _Float16* fA  = (_Float16*)featA;
    __half2*  fC  = (__half2*)featA;   // reuse: featA consumed by agg0_gemm1 before write

    // 1) gemm0 + cursor init
    kernelA<<<783, 256, 0, stream>>>(x, W0, al0, ar0, fA, el2A, er2A, bcursor, N);
    // 2) CSR: partition + local sort
    int pb = (E + 1024 * PEPT - 1) / (1024 * PEPT);
    partition_edges<<<pb, 1024, 0, stream>>>(src, dst, bcursor, ebuf, E);
    local_sort<<<NBKT, 256, 0, stream>>>(ebuf, bcursor, rowse, csrc, N);

    int nb4 = (N + 3) / 4;
    // 3) layer-0 aggregate + fused fp32 gemm1 + layer-1 logits
    agg0_gemm1<<<2048, 256, 0, stream>>>(rowse, csrc, el2A, er2A, fA,
                                         b0, W1, al1, ar1, featB, el2B, er2B, N);
    // 4) layer-1 aggregate + fused fp32 gemm2 (W2 in LDS) + layer-2 logits
    //    (replaces aggregate32 + gemm_mfma2; el2A/er2A reused for layer-2 logits)
    agg1_gemm2<<<2048, 256, 0, stream>>>(rowse, csrc, el2B, er2B, featB,
                                         b1, W2, al2, ar2, fC, el2A, er2A, N);
    // 5) layer-2 aggregate, mean over heads
    aggregate64_mean<<<nb4, 256, 0, stream>>>(rowse, csrc, el2A, er2A, fC, b2, out, N);
}

// Round 19
// 246.408 us; speedup vs baseline: 1.2903x; 1.2903x over previous
//
#include <hip/hip_runtime.h>
#include <hip/hip_bf16.h>
#include <hip/hip_fp16.h>

#define NNODES 50000
#define NEG_SLOPE 0.2f
#define BKT_SHIFT 8
#define NBKT ((NNODES + 255) >> 8)   // 196 buckets of 256 dsts
#define STRIDE 5120                   // fixed slots per bucket (avg 4082, +16 sigma)
#define PEPT 8                        // partition: edges per thread

typedef _Float16 half8 __attribute__((ext_vector_type(8)));
typedef float v4f __attribute__((ext_vector_type(4)));

__device__ __forceinline__ int rfl(int v) { return __builtin_amdgcn_readfirstlane(v); }

// pack W[K][C] fp32 into MFMA B-fragment order
__device__ __forceinline__ void pack_one(const float* W, _Float16* Wp, int K, int C, int tid) {
    int KC = K / 32;
    int l = tid & 63;
    int kc = (tid >> 6) % KC;
    int t = tid / (KC * 64);
    int cc = l & 15, q = l >> 4;
    half8 b;
#pragma unroll
    for (int j = 0; j < 8; j++)
        b[j] = (_Float16)W[(size_t)(kc * 32 + q * 8 + j) * C + t * 16 + cc];
    *(half8*)(Wp + (size_t)tid * 8) = b;
}

// ---------------- Kernel A: gemm0 (on-the-fly W0 pack) + cursor init + Wp2 pack ----
__global__ __launch_bounds__(256) void kernelA(
    const float* __restrict__ x, const float* __restrict__ W0,
    const float* __restrict__ AL, const float* __restrict__ AR,
    _Float16* __restrict__ featA, float2* __restrict__ el2A, float2* __restrict__ er2A,
    int* __restrict__ bcursor,
    const float* __restrict__ W2, _Float16* __restrict__ Wp2, int N) {
    int blk = blockIdx.x;
    if (blk == 782) {
        if (threadIdx.x < NBKT) bcursor[threadIdx.x * 16] = threadIdx.x * STRIDE;
        return;
    }
    if (blk > 782) {
        int tid = (blk - 783) * 256 + threadIdx.x;
        if (tid < 8 * 2 * 64) pack_one(W2, Wp2, 64, 128, tid);
        return;
    }
    int wave = threadIdx.x >> 6, lane = threadIdx.x & 63;
    int mtile = blk * 4 + wave;
    if (mtile * 16 >= N) return;
    int m0 = mtile * 16;
    int c = lane & 15, q = lane >> 4;
    v4f acc[4];
#pragma unroll
    for (int t = 0; t < 4; t++) acc[t] = (v4f){0.f, 0.f, 0.f, 0.f};
    const size_t arow = (size_t)(m0 + c) * 128 + q * 8;
#pragma unroll
    for (int kc = 0; kc < 4; kc++) {
        const float* xr = x + arow + kc * 32;
        float4 f0 = *(const float4*)xr;
        float4 f1 = *(const float4*)(xr + 4);
        float fv[8] = {f0.x, f0.y, f0.z, f0.w, f1.x, f1.y, f1.z, f1.w};
        half8 ah, av;
#pragma unroll
        for (int j = 0; j < 8; j++) {
            ah[j] = (_Float16)fv[j];
            av[j] = (_Float16)(fv[j] - (float)ah[j]);
        }
#pragma unroll
        for (int tt = 0; tt < 4; tt++) {
            half8 b;
#pragma unroll
            for (int j = 0; j < 8; j++)
                b[j] = (_Float16)W0[(size_t)(kc * 32 + q * 8 + j) * 64 + tt * 16 + c];
            acc[tt] = __builtin_amdgcn_mfma_f32_16x16x32_f16(ah, b, acc[tt], 0, 0, 0);
            acc[tt] = __builtin_amdgcn_mfma_f32_16x16x32_f16(av, b, acc[tt], 0, 0, 0);
        }
    }
#pragma unroll
    for (int tt = 0; tt < 4; tt++)
#pragma unroll
        for (int r = 0; r < 4; r++) {
            int row = m0 + q * 4 + r;
            featA[(size_t)row * 64 + tt * 16 + c] = (_Float16)acc[tt][r];
        }
    float alv[4], arv[4];
#pragma unroll
    for (int tt = 0; tt < 4; tt++) { alv[tt] = AL[tt * 16 + c]; arv[tt] = AR[tt * 16 + c]; }
#pragma unroll
    for (int r = 0; r < 4; r++) {
        float l0 = 0.f, l1 = 0.f, r0 = 0.f, r1 = 0.f;
#pragma unroll
        for (int tt = 0; tt < 4; tt++) {
            float v = acc[tt][r];
            if (tt < 2) { l0 = fmaf(v, alv[tt], l0); r0 = fmaf(v, arv[tt], r0); }
            else        { l1 = fmaf(v, alv[tt], l1); r1 = fmaf(v, arv[tt], r1); }
        }
#pragma unroll
        for (int m = 1; m < 16; m <<= 1) {
            l0 += __shfl_xor(l0, m, 64);
            l1 += __shfl_xor(l1, m, 64);
            r0 += __shfl_xor(r0, m, 64);
            r1 += __shfl_xor(r1, m, 64);
        }
        if (c == 0) {
            int row = m0 + q * 4 + r;
            el2A[row] = make_float2(l0, l1);
            er2A[row] = make_float2(r0, r1);
        }
    }
}

// ---------------- partition: block-privatized, fixed bucket regions ----------------
__global__ __launch_bounds__(1024) void partition_edges(
    const int* __restrict__ src, const int* __restrict__ dst,
    int* __restrict__ bcursor, int2* __restrict__ ebuf, int E) {
    __shared__ int hist[NBKT];
    __shared__ int gbase[NBKT];
    int t = threadIdx.x;
    for (int i = t; i < NBKT; i += 1024) hist[i] = 0;
    __syncthreads();
    int base = blockIdx.x * 1024 * PEPT;
    int sreg[PEPT], dreg[PEPT], rreg[PEPT], breg[PEPT];
#pragma unroll
    for (int k = 0; k < PEPT; k++) {
        int i = base + k * 1024 + t;
        if (i < E) {
            sreg[k] = src[i];
            dreg[k] = dst[i];
            breg[k] = dreg[k] >> BKT_SHIFT;
            rreg[k] = atomicAdd(&hist[breg[k]], 1);
        } else {
            breg[k] = -1;
        }
    }
    __syncthreads();
    for (int i = t; i < NBKT; i += 1024)
        if (hist[i]) gbase[i] = atomicAdd(&bcursor[i * 16], hist[i]);
    __syncthreads();
#pragma unroll
    for (int k = 0; k < PEPT; k++) {
        if (breg[k] >= 0)
            ebuf[(size_t)(gbase[breg[k]] + rreg[k])] = make_int2(sreg[k], dreg[k]);
    }
}

// ---------------- local sort: per-bucket degree count + scan -> rowse + csrc ----
__global__ __launch_bounds__(256) void local_sort(const int2* __restrict__ ebuf,
                                                  const int* __restrict__ bcursor,
                                                  int2* __restrict__ rowse,
                                                  int* __restrict__ csrc, int N) {
    __shared__ int lcnt[256], lrow[256], ws[4];
    int b = blockIdx.x;
    int d0 = b << BKT_SHIFT;
    int t = threadIdx.x;
    int base = b * STRIDE;
    int endE = bcursor[b * 16];
    lcnt[t] = 0;
    __syncthreads();
    for (int i = base + t; i < endE; i += 256)
        atomicAdd(&lcnt[ebuf[i].y - d0], 1);
    __syncthreads();
    int v = lcnt[t];
    int lane = t & 63;
    int x = v;
#pragma unroll
    for (int m = 1; m < 64; m <<= 1) {
        int y = __shfl_up(x, m, 64);
        if (lane >= m) x += y;
    }
    if (lane == 63) ws[t >> 6] = x;
    __syncthreads();
    int w = t >> 6, waveoff = 0;
#pragma unroll
    for (int k = 0; k < 4; k++) if (k < w) waveoff += ws[k];
    int excl = base + waveoff + x - v;
    lrow[t] = excl;
    int d = d0 + t;
    if (d < N) rowse[d] = make_int2(excl, excl + v);
    lcnt[t] = 0;
    __syncthreads();
    for (int i = base + t; i < endE; i += 256) {
        int2 e = ebuf[i];
        int ld = e.y - d0;
        int p = lrow[ld] + atomicAdd(&lcnt[ld], 1);
        csrc[p] = e.x;
    }
}

// ---------------- agg0 + fused fp32 matvec gemm1 (64->64) + layer-1 logits ----
// Plain __launch_bounds__(256): natural VGPR ~64, no spill (R14/R15 lesson:
// any VGPR cap below natural -> scratch-bound). Gather is latency-plateau-bound;
// occupancy levers measured flat (R16/R17).
__global__ __launch_bounds__(256) void agg0_gemm1(
    const int2* __restrict__ rowse, const int* __restrict__ csrc,
    const float2* __restrict__ el2A, const float2* __restrict__ er2A,
    const _Float16* __restrict__ featA, const float* __restrict__ b0,
    const float* __restrict__ W1, const float* __restrict__ al1, const float* __restrict__ ar1,
    _Float16* __restrict__ featB, float2* __restrict__ el2B, float2* __restrict__ er2B,
    int N) {
    __shared__ int2 stA[4][64], stB[4][64];
    __shared__ float vbuf[4][64];
    int wave = threadIdx.x >> 6, lane = threadIdx.x & 63, h = lane >> 5;
    float bl = b0[lane];
    float w1r[64];
#pragma unroll
    for (int k = 0; k < 64; k++) w1r[k] = W1[k * 64 + lane];
    float al1v = al1[lane], ar1v = ar1[lane];
    const int2* stH = h ? stB[wave] : stA[wave];
    for (int n0 = blockIdx.x * 4 + wave; n0 < N; n0 += gridDim.x * 4) {
        int n = rfl(n0);
        int2 se = rowse[n];
        int beg = rfl(se.x), end = rfl(se.y);
        float2 rr = er2A[n];
        float s = 0.f, acc = 0.f;
        for (int base = beg; base < end; base += 64) {
            int idx = base + lane;
            int sv = 0; float wxv = 0.f, wyv = 0.f;
            if (idx < end) {
                sv = csrc[idx];
                float2 l = el2A[sv];
                float t0 = l.x + rr.x; t0 = t0 > 0.f ? t0 : NEG_SLOPE * t0;
                float t1 = l.y + rr.y; t1 = t1 > 0.f ? t1 : NEG_SLOPE * t1;
                wxv = __expf(t0); wyv = __expf(t1);
            }
            stA[wave][lane] = make_int2(sv, __float_as_int(wxv));
            stB[wave][lane] = make_int2(sv, __float_as_int(wyv));
            int cnt = min(64, end - base);
            int j = 0;
            for (; j + 7 < cnt; j += 8) {
                int4 e01 = *(const int4*)(stH + j);
                int4 e23 = *(const int4*)(stH + j + 2);
                int4 e45 = *(const int4*)(stH + j + 4);
                int4 e67 = *(const int4*)(stH + j + 6);
                float f0 = (float)featA[(size_t)e01.x * 64 + lane];
                float f1 = (float)featA[(size_t)e01.z * 64 + lane];
                float f2 = (float)featA[(size_t)e23.x * 64 + lane];
                float f3 = (float)featA[(size_t)e23.z * 64 + lane];
                float f4 = (float)featA[(size_t)e45.x * 64 + lane];
                float f5 = (float)featA[(size_t)e45.z * 64 + lane];
                float f6 = (float)featA[(size_t)e67.x * 64 + lane];
                float f7 = (float)featA[(size_t)e67.z * 64 + lane];
                float w0 = __int_as_float(e01.y), w1 = __int_as_float(e01.w);
                float w2 = __int_as_float(e23.y), w3 = __int_as_float(e23.w);
                float w4 = __int_as_float(e45.y), w5 = __int_as_float(e45.w);
                float w6 = __int_as_float(e67.y), w7 = __int_as_float(e67.w);
                s += ((w0 + w1) + (w2 + w3)) + ((w4 + w5) + (w6 + w7));
                acc = fmaf(w0, f0, acc);
                acc = fmaf(w1, f1, acc);
                acc = fmaf(w2, f2, acc);
                acc = fmaf(w3, f3, acc);
                acc = fmaf(w4, f4, acc);
                acc = fmaf(w5, f5, acc);
                acc = fmaf(w6, f6, acc);
                acc = fmaf(w7, f7, acc);
            }
            for (; j < cnt; j++) {
                int2 e = stH[j];
                float w0 = __int_as_float(e.y);
                float f0 = (float)featA[(size_t)e.x * 64 + lane];
                s += w0;
                acc = fmaf(w0, f0, acc);
            }
        }
        float v = (s > 0.f) ? acc / s : 0.f;
        v = fmaxf(v + bl, 0.f);
        vbuf[wave][lane] = v;
        const float4* vv = (const float4*)vbuf[wave];
        float f = 0.f;
#pragma unroll
        for (int kk = 0; kk < 16; kk++) {
            float4 v4 = vv[kk];
            f = fmaf(v4.x, w1r[4 * kk + 0], f);
            f = fmaf(v4.y, w1r[4 * kk + 1], f);
            f = fmaf(v4.z, w1r[4 * kk + 2], f);
            f = fmaf(v4.w, w1r[4 * kk + 3], f);
        }
        featB[(size_t)n * 64 + lane] = (_Float16)f;
        float vl = f * al1v, vr = f * ar1v;
#pragma unroll
        for (int m = 1; m < 32; m <<= 1) {
            vl += __shfl_xor(vl, m, 64);
            vr += __shfl_xor(vr, m, 64);
        }
        if ((lane & 31) == 0) {
            ((float*)el2B)[n * 2 + h] = vl;
            ((float*)er2B)[n * 2 + h] = vr;
        }
    }
}

// ---------------- agg1 (layer 1): outputs hi/lo fp16 for MFMA gemm2 ----------------
__global__ __launch_bounds__(256) void aggregate32(
    const int2* __restrict__ rowse, const int* __restrict__ csrc,
    const float2* __restrict__ el2, const float2* __restrict__ er2,
    const _Float16* __restrict__ feat16, const float* __restrict__ b,
    _Float16* __restrict__ ahi, _Float16* __restrict__ alo, int N) {
    __shared__ int2 stA[4][64], stB[4][64];
    int wave = threadIdx.x >> 6, lane = threadIdx.x & 63, h = lane >> 5;
    int n = rfl(blockIdx.x * 4 + wave);
    if (n >= N) return;
    float bl = b[lane];
    int2 se = rowse[n];
    int beg = rfl(se.x), end = rfl(se.y);
    float2 rr = er2[n];
    const int2* stH = h ? stB[wave] : stA[wave];
    float s = 0.f, acc = 0.f;
    for (int base = beg; base < end; base += 64) {
        int idx = base + lane;
        int sv = 0; float wxv = 0.f, wyv = 0.f;
        if (idx < end) {
            sv = csrc[idx];
            float2 l = el2[sv];
            float t0 = l.x + rr.x; t0 = t0 > 0.f ? t0 : NEG_SLOPE * t0;
            float t1 = l.y + rr.y; t1 = t1 > 0.f ? t1 : NEG_SLOPE * t1;
            wxv = __expf(t0); wyv = __expf(t1);
        }
        stA[wave][lane] = make_int2(sv, __float_as_int(wxv));
        stB[wave][lane] = make_int2(sv, __float_as_int(wyv));
        int cnt = min(64, end - base);
        int j = 0;
        for (; j + 7 < cnt; j += 8) {
            int4 e01 = *(const int4*)(stH + j);
            int4 e23 = *(const int4*)(stH + j + 2);
            int4 e45 = *(const int4*)(stH + j + 4);
            int4 e67 = *(const int4*)(stH + j + 6);
            float f0 = (float)feat16[(size_t)e01.x * 64 + lane];
            float f1 = (float)feat16[(size_t)e01.z * 64 + lane];
            float f2 = (float)feat16[(size_t)e23.x * 64 + lane];
            float f3 = (float)feat16[(size_t)e23.z * 64 + lane];
            float f4 = (float)feat16[(size_t)e45.x * 64 + lane];
            float f5 = (float)feat16[(size_t)e45.z * 64 + lane];
            float f6 = (float)feat16[(size_t)e67.x * 64 + lane];
            float f7 = (float)feat16[(size_t)e67.z * 64 + lane];
            float w0 = __int_as_float(e01.y), w1 = __int_as_float(e01.w);
            float w2 = __int_as_float(e23.y), w3 = __int_as_float(e23.w);
            float w4 = __int_as_float(e45.y), w5 = __int_as_float(e45.w);
            float w6 = __int_as_float(e67.y), w7 = __int_as_float(e67.w);
            s += ((w0 + w1) + (w2 + w3)) + ((w4 + w5) + (w6 + w7));
            acc = fmaf(w0, f0, acc);
            acc = fmaf(w1, f1, acc);
            acc = fmaf(w2, f2, acc);
            acc = fmaf(w3, f3, acc);
            acc = fmaf(w4, f4, acc);
            acc = fmaf(w5, f5, acc);
            acc = fmaf(w6, f6, acc);
            acc = fmaf(w7, f7, acc);
        }
        for (; j < cnt; j++) {
            int2 e = stH[j];
            float w0 = __int_as_float(e.y);
            float f0 = (float)feat16[(size_t)e.x * 64 + lane];
            s += w0;
            acc = fmaf(w0, f0, acc);
        }
    }
    float v = (s > 0.f) ? acc / s : 0.f;
    v = fmaxf(v + bl, 0.f);
    _Float16 hv = (_Float16)v;
    ahi[(size_t)n * 64 + lane] = hv;
    alo[(size_t)n * 64 + lane] = (_Float16)(v - (float)hv);
}

// ---------------- gemm2: MFMA 64->128, half2-interleaved feat + layer-2 logits ----
__global__ __launch_bounds__(256) void gemm_mfma2(
    const _Float16* __restrict__ Ahi, const _Float16* __restrict__ Alo,
    const _Float16* __restrict__ Wp,
    const float* __restrict__ AL, const float* __restrict__ AR,
    __half2* __restrict__ feat2, float2* __restrict__ el2, float2* __restrict__ er2,
    int N) {
    constexpr int KC = 2, NT = 8;
    int wave = threadIdx.x >> 6, lane = threadIdx.x & 63;
    int mtile = blockIdx.x * 4 + wave;
    if (mtile * 16 >= N) return;
    int m0 = mtile * 16;
    int c = lane & 15, q = lane >> 4;
    v4f acc[NT];
#pragma unroll
    for (int t = 0; t < NT; t++) acc[t] = (v4f){0.f, 0.f, 0.f, 0.f};
    const size_t arow = (size_t)(m0 + c) * 64 + q * 8;
#pragma unroll
    for (int kc = 0; kc < KC; kc++) {
        half8 ah = *(const half8*)(Ahi + arow + kc * 32);
        half8 av = *(const half8*)(Alo + arow + kc * 32);
#pragma unroll
        for (int t = 0; t < NT; t++) {
            half8 b = *(const half8*)(Wp + ((size_t)(t * KC + kc) * 64 + lane) * 8);
            acc[t] = __builtin_amdgcn_mfma_f32_16x16x32_f16(ah, b, acc[t], 0, 0, 0);
            acc[t] = __builtin_amdgcn_mfma_f32_16x16x32_f16(av, b, acc[t], 0, 0, 0);
        }
    }
#pragma unroll
    for (int t = 0; t < NT / 2; t++)
#pragma unroll
        for (int r = 0; r < 4; r++) {
            int row = m0 + q * 4 + r;
            feat2[(size_t)row * 64 + t * 16 + c] =
                __floats2half2_rn(acc[t][r], acc[t + NT / 2][r]);
        }
    float alv[NT], arv[NT];
#pragma unroll
    for (int t = 0; t < NT; t++) { alv[t] = AL[t * 16 + c]; arv[t] = AR[t * 16 + c]; }
#pragma unroll
    for (int r = 0; r < 4; r++) {
        float l0 = 0.f, l1 = 0.f, r0 = 0.f, r1 = 0.f;
#pragma unroll
        for (int t = 0; t < NT; t++) {
            float v = acc[t][r];
            if (t < NT / 2) { l0 = fmaf(v, alv[t], l0); r0 = fmaf(v, arv[t], r0); }
            else            { l1 = fmaf(v, alv[t], l1); r1 = fmaf(v, arv[t], r1); }
        }
#pragma unroll
        for (int m = 1; m < 16; m <<= 1) {
            l0 += __shfl_xor(l0, m, 64);
            l1 += __shfl_xor(l1, m, 64);
            r0 += __shfl_xor(r0, m, 64);
            r1 += __shfl_xor(r1, m, 64);
        }
        if (c == 0) {
            int row = m0 + q * 4 + r;
            el2[row] = make_float2(l0, l1);
            er2[row] = make_float2(r0, r1);
        }
    }
}

// ---------------- agg2: both heads via half2; mean over heads ----------------
__global__ __launch_bounds__(256) void aggregate64_mean(
    const int2* __restrict__ rowse, const int* __restrict__ csrc,
    const float2* __restrict__ el2, const float2* __restrict__ er2,
    const __half2* __restrict__ feat2, const float* __restrict__ b,
    float* __restrict__ out, int N) {
    __shared__ int4 st[4][64];
    int wave = threadIdx.x >> 6, lane = threadIdx.x & 63;
    int n = rfl(blockIdx.x * 4 + wave);
    if (n >= N) return;
    float b0 = b[lane], b1 = b[64 + lane];
    int2 se = rowse[n];
    int beg = rfl(se.x), end = rfl(se.y);
    float2 rr = er2[n];
    float s0 = 0.f, s1 = 0.f, a0 = 0.f, a1 = 0.f;
    for (int base = beg; base < end; base += 64) {
        int idx = base + lane;
        int sv = 0; float wxv = 0.f, wyv = 0.f;
        if (idx < end) {
            sv = csrc[idx];
            float2 l = el2[sv];
            float t0 = l.x + rr.x; t0 = t0 > 0.f ? t0 : NEG_SLOPE * t0;
            float t1 = l.y + rr.y; t1 = t1 > 0.f ? t1 : NEG_SLOPE * t1;
            wxv = __expf(t0); wyv = __expf(t1);
        }
        st[wave][lane] = make_int4(sv, __float_as_int(wxv), __float_as_int(wyv), 0);
        int cnt = min(64, end - base);
        int j = 0;
        for (; j + 7 < cnt; j += 8) {
            float2 fv[8]; float wxs[8], wys[8];
#pragma unroll
            for (int u = 0; u < 8; u++) {
                int4 e = st[wave][j + u];
                wxs[u] = __int_as_float(e.y);
                wys[u] = __int_as_float(e.z);
                fv[u] = __half22float2(feat2[(size_t)e.x * 64 + lane]);
            }
#pragma unroll
            for (int u = 0; u < 8; u++) {
                s0 += wxs[u]; s1 += wys[u];
                a0 = fmaf(wxs[u], fv[u].x, a0);
                a1 = fmaf(wys[u], fv[u].y, a1);
            }
        }
        for (; j < cnt; j++) {
            int4 e = st[wave][j];
            float wx0 = __int_as_float(e.y), wy0 = __int_as_float(e.z);
            float2 f0 = __half22float2(feat2[(size_t)e.x * 64 + lane]);
            s0 += wx0; s1 += wy0;
            a0 = fmaf(wx0, f0.x, a0); a1 = fmaf(wy0, f0.y, a1);
        }
    }
    float v0 = (s0 > 0.f) ? a0 / s0 : 0.f;
    float v1 = (s1 > 0.f) ? a1 / s1 : 0.f;
    out[(size_t)n * 64 + lane] = 0.5f * ((v0 + b0) + (v1 + b1));
}

// ---------------- launcher ----------------

extern "C" void kernel_launch(void* const* d_in, const int* in_sizes, int n_in,
                              void* d_out, int out_size, void* d_ws, size_t ws_size,
                              hipStream_t stream) {
    const float* x   = (const float*)d_in[0];
    const int*   src = (const int*)d_in[1];
    const int*   dst = (const int*)d_in[2];
    const float* W0  = (const float*)d_in[3];
    const float* al0 = (const float*)d_in[4];
    const float* ar0 = (const float*)d_in[5];
    const float* b0  = (const float*)d_in[6];
    const float* W1  = (const float*)d_in[7];
    const float* al1 = (const float*)d_in[8];
    const float* ar1 = (const float*)d_in[9];
    const float* b1  = (const float*)d_in[10];
    const float* W2  = (const float*)d_in[11];
    const float* al2 = (const float*)d_in[12];
    const float* ar2 = (const float*)d_in[13];
    const float* b2  = (const float*)d_in[14];
    float* out = (float*)d_out;

    const int N = NNODES;
    const int E = in_sizes[1];

    char* p = (char*)d_ws;
    auto alloc = [&](size_t bytes) {
        void* r = (void*)p;
        p += (bytes + 255) & ~(size_t)255;
        return r;
    };
    int*    bcursor = (int*)alloc((size_t)NBKT * 16 * 4);
    int2*   rowse   = (int2*)alloc((size_t)N * 8);
    int2*   ebuf    = (int2*)alloc(((size_t)NBKT * STRIDE + 4096) * 8);
    int*    csrc    = (int*)alloc(((size_t)NBKT * STRIDE + 4096) * 4);
    float2* el2A    = (float2*)alloc((size_t)N * 8);
    float2* er2A    = (float2*)alloc((size_t)N * 8);
    float2* el2B    = (float2*)alloc((size_t)N * 8);
    float2* er2B    = (float2*)alloc((size_t)N * 8);
    _Float16* ahi   = (_Float16*)alloc((size_t)N * 64 * 2);
    _Float16* alo   = (_Float16*)alloc((size_t)N * 64 * 2);
    void*   featA   = alloc((size_t)N * 64 * 4);
    _Float16* featB = (_Float16*)alloc((size_t)N * 64 * 2);
    _Float16* Wp2   = (_Float16*)alloc(8 * 2 * 64 * 8 * 2);

    // 1) gemm0 + cursor init + Wp2 pack
    kernelA<<<787, 256, 0, stream>>>(x, W0, al0, ar0, (_Float16*)featA, el2A, er2A,
                                     bcursor, W2, Wp2, N);
    // 2) CSR: partition + local sort
    int pb = (E + 1024 * PEPT - 1) / (1024 * PEPT);
    partition_edges<<<pb, 1024, 0, stream>>>(src, dst, bcursor, ebuf, E);
    local_sort<<<NBKT, 256, 0, stream>>>(ebuf, bcursor, rowse, csrc, N);

    int nb4 = (N + 3) / 4;
    // 3) layer-0 aggregate + fused fp32 gemm1 + layer-1 logits
    agg0_gemm1<<<2048, 256, 0, stream>>>(rowse, csrc, el2A, er2A, (const _Float16*)featA,
                                         b0, W1, al1, ar1, featB, el2B, er2B, N);
    // 4) layer-1 aggregate -> hi/lo fp16
    aggregate32<<<nb4, 256, 0, stream>>>(rowse, csrc, el2B, er2B, featB, b1, ahi, alo, N);
    // 5) gemm2 MFMA (64->128)
    int gb = (N / 16 + 3) / 4;
    gemm_mfma2<<<gb, 256, 0, stream>>>(ahi, alo, Wp2, al2, ar2, (__half2*)featA, el2A, er2A, N);
    // 6) layer-2 aggregate, mean over heads
    aggregate64_mean<<<nb4, 256, 0, stream>>>(rowse, csrc, el2A, er2A, (const __half2*)featA,
                                              b2, out, N);
}

// Round 20
// 242.098 us; speedup vs baseline: 1.3132x; 1.0178x over previous
//
#include <hip/hip_runtime.h>
#include <hip/hip_bf16.h>
#include <hip/hip_fp16.h>

#define NNODES 50000
#define NEG_SLOPE 0.2f
#define BKT_SHIFT 8
#define NBKT ((NNODES + 255) >> 8)   // 196 buckets of 256 dsts
#define STRIDE 5120                   // fixed slots per bucket (avg 4082, +16 sigma)
#define PCHUNK 2048                   // partition chunk (256 thr x 8 edges)
#define PEPT 8

typedef _Float16 half8 __attribute__((ext_vector_type(8)));
typedef float v4f __attribute__((ext_vector_type(4)));

__device__ __forceinline__ int rfl(int v) { return __builtin_amdgcn_readfirstlane(v); }

// pack W[K][C] fp32 into MFMA B-fragment order
__device__ __forceinline__ void pack_one(const float* W, _Float16* Wp, int K, int C, int tid) {
    int KC = K / 32;
    int l = tid & 63;
    int kc = (tid >> 6) % KC;
    int t = tid / (KC * 64);
    int cc = l & 15, q = l >> 4;
    half8 b;
#pragma unroll
    for (int j = 0; j < 8; j++)
        b[j] = (_Float16)W[(size_t)(kc * 32 + q * 8 + j) * C + t * 16 + cc];
    *(half8*)(Wp + (size_t)tid * 8) = b;
}

// ---------------- Kernel AB: gemm0 + Wp2 pack + edge partition, ONE launch ----------
// The three jobs are mutually independent (partition cursors count from zero;
// bcursor is memset'd async before this kernel). Heterogeneous blocks:
//   [0, 782)      : MFMA gemm0 (x fp32, in-register hi/lo split, on-the-fly W0 pack)
//   [782, 786)    : pack W2 into MFMA B-fragment order
//   [786, 786+nch): block-privatized partition, chunk = 2048 edges
__global__ __launch_bounds__(256) void kernelAB(
    const float* __restrict__ x, const float* __restrict__ W0,
    const float* __restrict__ AL, const float* __restrict__ AR,
    _Float16* __restrict__ featA, float2* __restrict__ el2A, float2* __restrict__ er2A,
    const float* __restrict__ W2, _Float16* __restrict__ Wp2,
    const int* __restrict__ src, const int* __restrict__ dst,
    int* __restrict__ bcursor, int2* __restrict__ ebuf, int E, int N) {
    int blk = blockIdx.x;
    if (blk >= 786) {
        // ---- partition branch ----
        __shared__ int hist[NBKT];
        __shared__ int gbase[NBKT];
        int t = threadIdx.x;
        for (int i = t; i < NBKT; i += 256) hist[i] = 0;
        __syncthreads();
        int base = (blk - 786) * PCHUNK;
        int sreg[PEPT], dreg[PEPT], rreg[PEPT], breg[PEPT];
#pragma unroll
        for (int k = 0; k < PEPT; k++) {
            int i = base + k * 256 + t;
            if (i < E) {
                sreg[k] = src[i];
                dreg[k] = dst[i];
                breg[k] = dreg[k] >> BKT_SHIFT;
                rreg[k] = atomicAdd(&hist[breg[k]], 1);
            } else {
                breg[k] = -1;
            }
        }
        __syncthreads();
        for (int i = t; i < NBKT; i += 256)
            if (hist[i]) gbase[i] = i * STRIDE + atomicAdd(&bcursor[i * 16], hist[i]);
        __syncthreads();
#pragma unroll
        for (int k = 0; k < PEPT; k++) {
            if (breg[k] >= 0)
                ebuf[(size_t)(gbase[breg[k]] + rreg[k])] = make_int2(sreg[k], dreg[k]);
        }
        return;
    }
    if (blk >= 782) {
        int tid = (blk - 782) * 256 + threadIdx.x;
        if (tid < 8 * 2 * 64) pack_one(W2, Wp2, 64, 128, tid);
        return;
    }
    // ---- gemm0 branch ----
    int wave = threadIdx.x >> 6, lane = threadIdx.x & 63;
    int mtile = blk * 4 + wave;
    if (mtile * 16 >= N) return;
    int m0 = mtile * 16;
    int c = lane & 15, q = lane >> 4;
    v4f acc[4];
#pragma unroll
    for (int t = 0; t < 4; t++) acc[t] = (v4f){0.f, 0.f, 0.f, 0.f};
    const size_t arow = (size_t)(m0 + c) * 128 + q * 8;
#pragma unroll
    for (int kc = 0; kc < 4; kc++) {
        const float* xr = x + arow + kc * 32;
        float4 f0 = *(const float4*)xr;
        float4 f1 = *(const float4*)(xr + 4);
        float fv[8] = {f0.x, f0.y, f0.z, f0.w, f1.x, f1.y, f1.z, f1.w};
        half8 ah, av;
#pragma unroll
        for (int j = 0; j < 8; j++) {
            ah[j] = (_Float16)fv[j];
            av[j] = (_Float16)(fv[j] - (float)ah[j]);
        }
#pragma unroll
        for (int tt = 0; tt < 4; tt++) {
            half8 b;
#pragma unroll
            for (int j = 0; j < 8; j++)
                b[j] = (_Float16)W0[(size_t)(kc * 32 + q * 8 + j) * 64 + tt * 16 + c];
            acc[tt] = __builtin_amdgcn_mfma_f32_16x16x32_f16(ah, b, acc[tt], 0, 0, 0);
            acc[tt] = __builtin_amdgcn_mfma_f32_16x16x32_f16(av, b, acc[tt], 0, 0, 0);
        }
    }
#pragma unroll
    for (int tt = 0; tt < 4; tt++)
#pragma unroll
        for (int r = 0; r < 4; r++) {
            int row = m0 + q * 4 + r;
            featA[(size_t)row * 64 + tt * 16 + c] = (_Float16)acc[tt][r];
        }
    float alv[4], arv[4];
#pragma unroll
    for (int tt = 0; tt < 4; tt++) { alv[tt] = AL[tt * 16 + c]; arv[tt] = AR[tt * 16 + c]; }
#pragma unroll
    for (int r = 0; r < 4; r++) {
        float l0 = 0.f, l1 = 0.f, r0 = 0.f, r1 = 0.f;
#pragma unroll
        for (int tt = 0; tt < 4; tt++) {
            float v = acc[tt][r];
            if (tt < 2) { l0 = fmaf(v, alv[tt], l0); r0 = fmaf(v, arv[tt], r0); }
            else        { l1 = fmaf(v, alv[tt], l1); r1 = fmaf(v, arv[tt], r1); }
        }
#pragma unroll
        for (int m = 1; m < 16; m <<= 1) {
            l0 += __shfl_xor(l0, m, 64);
            l1 += __shfl_xor(l1, m, 64);
            r0 += __shfl_xor(r0, m, 64);
            r1 += __shfl_xor(r1, m, 64);
        }
        if (c == 0) {
            int row = m0 + q * 4 + r;
            el2A[row] = make_float2(l0, l1);
            er2A[row] = make_float2(r0, r1);
        }
    }
}

// ---------------- local sort: per-bucket degree count + scan -> rowse + csrc ----
// bcursor[b*16] now holds the bucket COUNT (partition counts from zero).
__global__ __launch_bounds__(256) void local_sort(const int2* __restrict__ ebuf,
                                                  const int* __restrict__ bcursor,
                                                  int2* __restrict__ rowse,
                                                  int* __restrict__ csrc, int N) {
    __shared__ int lcnt[256], lrow[256], ws[4];
    int b = blockIdx.x;
    int d0 = b << BKT_SHIFT;
    int t = threadIdx.x;
    int base = b * STRIDE;
    int endE = base + bcursor[b * 16];
    lcnt[t] = 0;
    __syncthreads();
    for (int i = base + t; i < endE; i += 256)
        atomicAdd(&lcnt[ebuf[i].y - d0], 1);
    __syncthreads();
    int v = lcnt[t];
    int lane = t & 63;
    int x = v;
#pragma unroll
    for (int m = 1; m < 64; m <<= 1) {
        int y = __shfl_up(x, m, 64);
        if (lane >= m) x += y;
    }
    if (lane == 63) ws[t >> 6] = x;
    __syncthreads();
    int w = t >> 6, waveoff = 0;
#pragma unroll
    for (int k = 0; k < 4; k++) if (k < w) waveoff += ws[k];
    int excl = base + waveoff + x - v;
    lrow[t] = excl;
    int d = d0 + t;
    if (d < N) rowse[d] = make_int2(excl, excl + v);
    lcnt[t] = 0;
    __syncthreads();
    for (int i = base + t; i < endE; i += 256) {
        int2 e = ebuf[i];
        int ld = e.y - d0;
        int p = lrow[ld] + atomicAdd(&lcnt[ld], 1);
        csrc[p] = e.x;
    }
}

// ---------------- agg0 + fused fp32 matvec gemm1 (64->64) + layer-1 logits ----
// Plain __launch_bounds__(256): natural VGPR ~64, no spill (R14/R15 lesson).
__global__ __launch_bounds__(256) void agg0_gemm1(
    const int2* __restrict__ rowse, const int* __restrict__ csrc,
    const float2* __restrict__ el2A, const float2* __restrict__ er2A,
    const _Float16* __restrict__ featA, const float* __restrict__ b0,
    const float* __restrict__ W1, const float* __restrict__ al1, const float* __restrict__ ar1,
    _Float16* __restrict__ featB, float2* __restrict__ el2B, float2* __restrict__ er2B,
    int N) {
    __shared__ int2 stA[4][64], stB[4][64];
    __shared__ float vbuf[4][64];
    int wave = threadIdx.x >> 6, lane = threadIdx.x & 63, h = lane >> 5;
    float bl = b0[lane];
    float w1r[64];
#pragma unroll
    for (int k = 0; k < 64; k++) w1r[k] = W1[k * 64 + lane];
    float al1v = al1[lane], ar1v = ar1[lane];
    const int2* stH = h ? stB[wave] : stA[wave];
    for (int n0 = blockIdx.x * 4 + wave; n0 < N; n0 += gridDim.x * 4) {
        int n = rfl(n0);
        int2 se = rowse[n];
        int beg = rfl(se.x), end = rfl(se.y);
        float2 rr = er2A[n];
        float s = 0.f, acc = 0.f;
        for (int base = beg; base < end; base += 64) {
            int idx = base + lane;
            int sv = 0; float wxv = 0.f, wyv = 0.f;
            if (idx < end) {
                sv = csrc[idx];
                float2 l = el2A[sv];
                float t0 = l.x + rr.x; t0 = t0 > 0.f ? t0 : NEG_SLOPE * t0;
                float t1 = l.y + rr.y; t1 = t1 > 0.f ? t1 : NEG_SLOPE * t1;
                wxv = __expf(t0); wyv = __expf(t1);
            }
            stA[wave][lane] = make_int2(sv, __float_as_int(wxv));
            stB[wave][lane] = make_int2(sv, __float_as_int(wyv));
            int cnt = min(64, end - base);
            int j = 0;
            for (; j + 7 < cnt; j += 8) {
                int4 e01 = *(const int4*)(stH + j);
                int4 e23 = *(const int4*)(stH + j + 2);
                int4 e45 = *(const int4*)(stH + j + 4);
                int4 e67 = *(const int4*)(stH + j + 6);
                float f0 = (float)featA[(size_t)e01.x * 64 + lane];
                float f1 = (float)featA[(size_t)e01.z * 64 + lane];
                float f2 = (float)featA[(size_t)e23.x * 64 + lane];
                float f3 = (float)featA[(size_t)e23.z * 64 + lane];
                float f4 = (float)featA[(size_t)e45.x * 64 + lane];
                float f5 = (float)featA[(size_t)e45.z * 64 + lane];
                float f6 = (float)featA[(size_t)e67.x * 64 + lane];
                float f7 = (float)featA[(size_t)e67.z * 64 + lane];
                float w0 = __int_as_float(e01.y), w1 = __int_as_float(e01.w);
                float w2 = __int_as_float(e23.y), w3 = __int_as_float(e23.w);
                float w4 = __int_as_float(e45.y), w5 = __int_as_float(e45.w);
                float w6 = __int_as_float(e67.y), w7 = __int_as_float(e67.w);
                s += ((w0 + w1) + (w2 + w3)) + ((w4 + w5) + (w6 + w7));
                acc = fmaf(w0, f0, acc);
                acc = fmaf(w1, f1, acc);
                acc = fmaf(w2, f2, acc);
                acc = fmaf(w3, f3, acc);
                acc = fmaf(w4, f4, acc);
                acc = fmaf(w5, f5, acc);
                acc = fmaf(w6, f6, acc);
                acc = fmaf(w7, f7, acc);
            }
            for (; j < cnt; j++) {
                int2 e = stH[j];
                float w0 = __int_as_float(e.y);
                float f0 = (float)featA[(size_t)e.x * 64 + lane];
                s += w0;
                acc = fmaf(w0, f0, acc);
            }
        }
        float v = (s > 0.f) ? acc / s : 0.f;
        v = fmaxf(v + bl, 0.f);
        vbuf[wave][lane] = v;
        const float4* vv = (const float4*)vbuf[wave];
        float f = 0.f;
#pragma unroll
        for (int kk = 0; kk < 16; kk++) {
            float4 v4 = vv[kk];
            f = fmaf(v4.x, w1r[4 * kk + 0], f);
            f = fmaf(v4.y, w1r[4 * kk + 1], f);
            f = fmaf(v4.z, w1r[4 * kk + 2], f);
            f = fmaf(v4.w, w1r[4 * kk + 3], f);
        }
        featB[(size_t)n * 64 + lane] = (_Float16)f;
        float vl = f * al1v, vr = f * ar1v;
#pragma unroll
        for (int m = 1; m < 32; m <<= 1) {
            vl += __shfl_xor(vl, m, 64);
            vr += __shfl_xor(vr, m, 64);
        }
        if ((lane & 31) == 0) {
            ((float*)el2B)[n * 2 + h] = vl;
            ((float*)er2B)[n * 2 + h] = vr;
        }
    }
}

// ---------------- agg1 (layer 1): outputs hi/lo fp16 for MFMA gemm2 ----------------
__global__ __launch_bounds__(256) void aggregate32(
    const int2* __restrict__ rowse, const int* __restrict__ csrc,
    const float2* __restrict__ el2, const float2* __restrict__ er2,
    const _Float16* __restrict__ feat16, const float* __restrict__ b,
    _Float16* __restrict__ ahi, _Float16* __restrict__ alo, int N) {
    __shared__ int2 stA[4][64], stB[4][64];
    int wave = threadIdx.x >> 6, lane = threadIdx.x & 63, h = lane >> 5;
    int n = rfl(blockIdx.x * 4 + wave);
    if (n >= N) return;
    float bl = b[lane];
    int2 se = rowse[n];
    int beg = rfl(se.x), end = rfl(se.y);
    float2 rr = er2[n];
    const int2* stH = h ? stB[wave] : stA[wave];
    float s = 0.f, acc = 0.f;
    for (int base = beg; base < end; base += 64) {
        int idx = base + lane;
        int sv = 0; float wxv = 0.f, wyv = 0.f;
        if (idx < end) {
            sv = csrc[idx];
            float2 l = el2[sv];
            float t0 = l.x + rr.x; t0 = t0 > 0.f ? t0 : NEG_SLOPE * t0;
            float t1 = l.y + rr.y; t1 = t1 > 0.f ? t1 : NEG_SLOPE * t1;
            wxv = __expf(t0); wyv = __expf(t1);
        }
        stA[wave][lane] = make_int2(sv, __float_as_int(wxv));
        stB[wave][lane] = make_int2(sv, __float_as_int(wyv));
        int cnt = min(64, end - base);
        int j = 0;
        for (; j + 7 < cnt; j += 8) {
            int4 e01 = *(const int4*)(stH + j);
            int4 e23 = *(const int4*)(stH + j + 2);
            int4 e45 = *(const int4*)(stH + j + 4);
            int4 e67 = *(const int4*)(stH + j + 6);
            float f0 = (float)feat16[(size_t)e01.x * 64 + lane];
            float f1 = (float)feat16[(size_t)e01.z * 64 + lane];
            float f2 = (float)feat16[(size_t)e23.x * 64 + lane];
            float f3 = (float)feat16[(size_t)e23.z * 64 + lane];
            float f4 = (float)feat16[(size_t)e45.x * 64 + lane];
            float f5 = (float)feat16[(size_t)e45.z * 64 + lane];
            float f6 = (float)feat16[(size_t)e67.x * 64 + lane];
            float f7 = (float)feat16[(size_t)e67.z * 64 + lane];
            float w0 = __int_as_float(e01.y), w1 = __int_as_float(e01.w);
            float w2 = __int_as_float(e23.y), w3 = __int_as_float(e23.w);
            float w4 = __int_as_float(e45.y), w5 = __int_as_float(e45.w);
            float w6 = __int_as_float(e67.y), w7 = __int_as_float(e67.w);
            s += ((w0 + w1) + (w2 + w3)) + ((w4 + w5) + (w6 + w7));
            acc = fmaf(w0, f0, acc);
            acc = fmaf(w1, f1, acc);
            acc = fmaf(w2, f2, acc);
            acc = fmaf(w3, f3, acc);
            acc = fmaf(w4, f4, acc);
            acc = fmaf(w5, f5, acc);
            acc = fmaf(w6, f6, acc);
            acc = fmaf(w7, f7, acc);
        }
        for (; j < cnt; j++) {
            int2 e = stH[j];
            float w0 = __int_as_float(e.y);
            float f0 = (float)feat16[(size_t)e.x * 64 + lane];
            s += w0;
            acc = fmaf(w0, f0, acc);
        }
    }
    float v = (s > 0.f) ? acc / s : 0.f;
    v = fmaxf(v + bl, 0.f);
    _Float16 hv = (_Float16)v;
    ahi[(size_t)n * 64 + lane] = hv;
    alo[(size_t)n * 64 + lane] = (_Float16)(v - (float)hv);
}

// ---------------- gemm2: MFMA 64->128, half2-interleaved feat + layer-2 logits ----
__global__ __launch_bounds__(256) void gemm_mfma2(
    const _Float16* __restrict__ Ahi, const _Float16* __restrict__ Alo,
    const _Float16* __restrict__ Wp,
    const float* __restrict__ AL, const float* __restrict__ AR,
    __half2* __restrict__ feat2, float2* __restrict__ el2, float2* __restrict__ er2,
    int N) {
    constexpr int KC = 2, NT = 8;
    int wave = threadIdx.x >> 6, lane = threadIdx.x & 63;
    int mtile = blockIdx.x * 4 + wave;
    if (mtile * 16 >= N) return;
    int m0 = mtile * 16;
    int c = lane & 15, q = lane >> 4;
    v4f acc[NT];
#pragma unroll
    for (int t = 0; t < NT; t++) acc[t] = (v4f){0.f, 0.f, 0.f, 0.f};
    const size_t arow = (size_t)(m0 + c) * 64 + q * 8;
#pragma unroll
    for (int kc = 0; kc < KC; kc++) {
        half8 ah = *(const half8*)(Ahi + arow + kc * 32);
        half8 av = *(const half8*)(Alo + arow + kc * 32);
#pragma unroll
        for (int t = 0; t < NT; t++) {
            half8 b = *(const half8*)(Wp + ((size_t)(t * KC + kc) * 64 + lane) * 8);
            acc[t] = __builtin_amdgcn_mfma_f32_16x16x32_f16(ah, b, acc[t], 0, 0, 0);
            acc[t] = __builtin_amdgcn_mfma_f32_16x16x32_f16(av, b, acc[t], 0, 0, 0);
        }
    }
#pragma unroll
    for (int t = 0; t < NT / 2; t++)
#pragma unroll
        for (int r = 0; r < 4; r++) {
            int row = m0 + q * 4 + r;
            feat2[(size_t)row * 64 + t * 16 + c] =
                __floats2half2_rn(acc[t][r], acc[t + NT / 2][r]);
        }
    float alv[NT], arv[NT];
#pragma unroll
    for (int t = 0; t < NT; t++) { alv[t] = AL[t * 16 + c]; arv[t] = AR[t * 16 + c]; }
#pragma unroll
    for (int r = 0; r < 4; r++) {
        float l0 = 0.f, l1 = 0.f, r0 = 0.f, r1 = 0.f;
#pragma unroll
        for (int t = 0; t < NT; t++) {
            float v = acc[t][r];
            if (t < NT / 2) { l0 = fmaf(v, alv[t], l0); r0 = fmaf(v, arv[t], r0); }
            else            { l1 = fmaf(v, alv[t], l1); r1 = fmaf(v, arv[t], r1); }
        }
#pragma unroll
        for (int m = 1; m < 16; m <<= 1) {
            l0 += __shfl_xor(l0, m, 64);
            l1 += __shfl_xor(l1, m, 64);
            r0 += __shfl_xor(r0, m, 64);
            r1 += __shfl_xor(r1, m, 64);
        }
        if (c == 0) {
            int row = m0 + q * 4 + r;
            el2[row] = make_float2(l0, l1);
            er2[row] = make_float2(r0, r1);
        }
    }
}

// ---------------- agg2: both heads via half2; mean over heads ----------------
__global__ __launch_bounds__(256) void aggregate64_mean(
    const int2* __restrict__ rowse, const int* __restrict__ csrc,
    const float2* __restrict__ el2, const float2* __restrict__ er2,
    const __half2* __restrict__ feat2, const float* __restrict__ b,
    float* __restrict__ out, int N) {
    __shared__ int4 st[4][64];
    int wave = threadIdx.x >> 6, lane = threadIdx.x & 63;
    int n = rfl(blockIdx.x * 4 + wave);
    if (n >= N) return;
    float b0 = b[lane], b1 = b[64 + lane];
    int2 se = rowse[n];
    int beg = rfl(se.x), end = rfl(se.y);
    float2 rr = er2[n];
    float s0 = 0.f, s1 = 0.f, a0 = 0.f, a1 = 0.f;
    for (int base = beg; base < end; base += 64) {
        int idx = base + lane;
        int sv = 0; float wxv = 0.f, wyv = 0.f;
        if (idx < end) {
            sv = csrc[idx];
            float2 l = el2[sv];
            float t0 = l.x + rr.x; t0 = t0 > 0.f ? t0 : NEG_SLOPE * t0;
            float t1 = l.y + rr.y; t1 = t1 > 0.f ? t1 : NEG_SLOPE * t1;
            wxv = __expf(t0); wyv = __expf(t1);
        }
        st[wave][lane] = make_int4(sv, __float_as_int(wxv), __float_as_int(wyv), 0);
        int cnt = min(64, end - base);
        int j = 0;
        for (; j + 7 < cnt; j += 8) {
            float2 fv[8]; float wxs[8], wys[8];
#pragma unroll
            for (int u = 0; u < 8; u++) {
                int4 e = st[wave][j + u];
                wxs[u] = __int_as_float(e.y);
                wys[u] = __int_as_float(e.z);
                fv[u] = __half22float2(feat2[(size_t)e.x * 64 + lane]);
            }
#pragma unroll
            for (int u = 0; u < 8; u++) {
                s0 += wxs[u]; s1 += wys[u];
                a0 = fmaf(wxs[u], fv[u].x, a0);
                a1 = fmaf(wys[u], fv[u].y, a1);
            }
        }
        for (; j < cnt; j++) {
            int4 e = st[wave][j];
            float wx0 = __int_as_float(e.y), wy0 = __int_as_float(e.z);
            float2 f0 = __half22float2(feat2[(size_t)e.x * 64 + lane]);
            s0 += wx0; s1 += wy0;
            a0 = fmaf(wx0, f0.x, a0); a1 = fmaf(wy0, f0.y, a1);
        }
    }
    float v0 = (s0 > 0.f) ? a0 / s0 : 0.f;
    float v1 = (s1 > 0.f) ? a1 / s1 : 0.f;
    out[(size_t)n * 64 + lane] = 0.5f * ((v0 + b0) + (v1 + b1));
}

// ---------------- launcher ----------------

extern "C" void kernel_launch(void* const* d_in, const int* in_sizes, int n_in,
                              void* d_out, int out_size, void* d_ws, size_t ws_size,
                              hipStream_t stream) {
    const float* x   = (const float*)d_in[0];
    const int*   src = (const int*)d_in[1];
    const int*   dst = (const int*)d_in[2];
    const float* W0  = (const float*)d_in[3];
    const float* al0 = (const float*)d_in[4];
    const float* ar0 = (const float*)d_in[5];
    const float* b0  = (const float*)d_in[6];
    const float* W1  = (const float*)d_in[7];
    const float* al1 = (const float*)d_in[8];
    const float* ar1 = (const float*)d_in[9];
    const float* b1  = (const float*)d_in[10];
    const float* W2  = (const float*)d_in[11];
    const float* al2 = (const float*)d_in[12];
    const float* ar2 = (const float*)d_in[13];
    const float* b2  = (const float*)d_in[14];
    float* out = (float*)d_out;

    const int N = NNODES;
    const int E = in_sizes[1];

    char* p = (char*)d_ws;
    auto alloc = [&](size_t bytes) {
        void* r = (void*)p;
        p += (bytes + 255) & ~(size_t)255;
        return r;
    };
    int*    bcursor = (int*)alloc((size_t)NBKT * 16 * 4);
    int2*   rowse   = (int2*)alloc((size_t)N * 8);
    int2*   ebuf    = (int2*)alloc(((size_t)NBKT * STRIDE + 4096) * 8);
    int*    csrc    = (int*)alloc(((size_t)NBKT * STRIDE + 4096) * 4);
    float2* el2A    = (float2*)alloc((size_t)N * 8);
    float2* er2A    = (float2*)alloc((size_t)N * 8);
    float2* el2B    = (float2*)alloc((size_t)N * 8);
    float2* er2B    = (float2*)alloc((size_t)N * 8);
    _Float16* ahi   = (_Float16*)alloc((size_t)N * 64 * 2);
    _Float16* alo   = (_Float16*)alloc((size_t)N * 64 * 2);
    void*   featA   = alloc((size_t)N * 64 * 4);
    _Float16* featB = (_Float16*)alloc((size_t)N * 64 * 2);
    _Float16* Wp2   = (_Float16*)alloc(8 * 2 * 64 * 8 * 2);

    // 0) zero bucket counters (partition counts from zero)
    hipMemsetAsync(bcursor, 0, (size_t)NBKT * 16 * 4, stream);
    // 1) gemm0 + Wp2 pack + partition, one launch (independent jobs overlap)
    int nch = (E + PCHUNK - 1) / PCHUNK;
    kernelAB<<<786 + nch, 256, 0, stream>>>(x, W0, al0, ar0, (_Float16*)featA, el2A, er2A,
                                            W2, Wp2, src, dst, bcursor, ebuf, E, N);
    // 2) local sort -> rowse + csrc
    local_sort<<<NBKT, 256, 0, stream>>>(ebuf, bcursor, rowse, csrc, N);

    int nb4 = (N + 3) / 4;
    // 3) layer-0 aggregate + fused fp32 gemm1 + layer-1 logits
    agg0_gemm1<<<2048, 256, 0, stream>>>(rowse, csrc, el2A, er2A, (const _Float16*)featA,
                                         b0, W1, al1, ar1, featB, el2B, er2B, N);
    // 4) layer-1 aggregate -> hi/lo fp16
    aggregate32<<<nb4, 256, 0, stream>>>(rowse, csrc, el2B, er2B, featB, b1, ahi, alo, N);
    // 5) gemm2 MFMA (64->128)
    int gb = (N / 16 + 3) / 4;
    gemm_mfma2<<<gb, 256, 0, stream>>>(ahi, alo, Wp2, al2, ar2, (__half2*)featA, el2A, er2A, N);
    // 6) layer-2 aggregate, mean over heads
    aggregate64_mean<<<nb4, 256, 0, stream>>>(rowse, csrc, el2A, er2A, (const __half2*)featA,
                                              b2, out, N);
}